// Round 2
// 419.289 us; speedup vs baseline: 1.0229x; 1.0229x over previous
//
#include <hip/hip_runtime.h>
#include <hip/hip_bf16.h>
#include <stdint.h>

// Problem constants (from reference setup_inputs)
#define M_DIM   32768        // B*S = 32*1024
#define IN_DIM  1152
#define OUT_DIM 1152
#define R_DIM   64
#define QMAXF   255.0f

#define RED_BLOCKS 2048
#define QBLOCKS    4096

typedef float  f32x4  __attribute__((ext_vector_type(4)));
typedef __bf16 bf16x8 __attribute__((ext_vector_type(8)));

// RNE float -> bf16 bits (finite inputs only)
static __device__ __forceinline__ unsigned short f2bf(float f) {
    unsigned int u = __float_as_uint(f);
    unsigned int r = (u + 0x7fffu + ((u >> 16) & 1u)) >> 16;
    return (unsigned short)r;
}

// ---------------- Pass 0: fold low-rank into weight (bf16) + reciprocal scales ----
// Wc[o][i] = quant_w[o][i] + sum_r left_w[o][r] * right_w[r][i];  rs[c] = 1/scales[c]
__global__ __launch_bounds__(256) void k_wprep(const float* __restrict__ qw,
                                               const float* __restrict__ rw,
                                               const float* __restrict__ lw,
                                               const float* __restrict__ scales,
                                               unsigned short* __restrict__ wc,
                                               float* __restrict__ rs) {
    int idx = blockIdx.x * 256 + threadIdx.x;   // over OUT*IN, exact grid
    if (idx < IN_DIM) rs[idx] = 1.0f / scales[idx];
    int o = idx / IN_DIM;
    int i = idx - o * IN_DIM;
    float acc = qw[idx];
    #pragma unroll 8
    for (int r = 0; r < R_DIM; r++)
        acc += lw[o * R_DIM + r] * rw[r * IN_DIM + i];
    wc[idx] = f2bf(acc);
}

// ---------------- Pass 1: global min/max of x * rs  (no division) ----------------
__global__ __launch_bounds__(256) void k_minmax(const float* __restrict__ x,
                                                const float* __restrict__ rs,
                                                float* __restrict__ partials) {
    const int n4 = (M_DIM * IN_DIM) / 4;      // 9,437,184 float4s
    int tid = blockIdx.x * 256 + threadIdx.x;
    const int stride = RED_BLOCKS * 256;
    float mn = 3.4e38f, mx = -3.4e38f;
    for (int i4 = tid; i4 < n4; i4 += stride) {
        int i = i4 * 4;
        float4 xv = *(const float4*)(x + i);
        int c = i % IN_DIM;                   // IN_DIM % 4 == 0 -> aligned
        float4 sv = *(const float4*)(rs + c);
        float a0 = xv.x * sv.x, a1 = xv.y * sv.y;
        float a2 = xv.z * sv.z, a3 = xv.w * sv.w;
        mn = fminf(mn, fminf(fminf(a0, a1), fminf(a2, a3)));
        mx = fmaxf(mx, fmaxf(fmaxf(a0, a1), fmaxf(a2, a3)));
    }
    #pragma unroll
    for (int off = 32; off > 0; off >>= 1) {
        mn = fminf(mn, __shfl_down(mn, off));
        mx = fmaxf(mx, __shfl_down(mx, off));
    }
    __shared__ float smn[4], smx[4];
    int lane = threadIdx.x & 63, wv = threadIdx.x >> 6;
    if (lane == 0) { smn[wv] = mn; smx[wv] = mx; }
    __syncthreads();
    if (threadIdx.x == 0) {
        float bmn = fminf(fminf(smn[0], smn[1]), fminf(smn[2], smn[3]));
        float bmx = fmaxf(fmaxf(smx[0], smx[1]), fmaxf(smx[2], smx[3]));
        partials[blockIdx.x * 2]     = bmn;
        partials[blockIdx.x * 2 + 1] = bmx;
    }
}

// ---------------- Pass 2: finalize quant params + per-column combined recip -------
__global__ __launch_bounds__(256) void k_finalize(const float* __restrict__ partials,
                                                  const float* __restrict__ scales,
                                                  float* __restrict__ qp,
                                                  float* __restrict__ comb) {
    float mn = 3.4e38f, mx = -3.4e38f;
    for (int i = threadIdx.x; i < RED_BLOCKS; i += 256) {
        mn = fminf(mn, partials[i * 2]);
        mx = fmaxf(mx, partials[i * 2 + 1]);
    }
    #pragma unroll
    for (int off = 32; off > 0; off >>= 1) {
        mn = fminf(mn, __shfl_down(mn, off));
        mx = fmaxf(mx, __shfl_down(mx, off));
    }
    __shared__ float smn[4], smx[4];
    __shared__ float s_qs;
    int lane = threadIdx.x & 63, wv = threadIdx.x >> 6;
    if (lane == 0) { smn[wv] = mn; smx[wv] = mx; }
    __syncthreads();
    if (threadIdx.x == 0) {
        float bmn = fminf(fminf(smn[0], smn[1]), fminf(smn[2], smn[3]));
        float bmx = fmaxf(fmaxf(smx[0], smx[1]), fmaxf(smx[2], smx[3]));
        float qs = (bmx - bmn) / QMAXF;
        float zp = rintf(-bmn / qs);
        qp[0] = qs;
        qp[1] = zp;
        qp[2] = -zp;            // clamp lo for (q - zp)
        qp[3] = QMAXF - zp;     // clamp hi for (q - zp)
        s_qs = qs;
    }
    __syncthreads();
    float qs = s_qs;
    for (int c = threadIdx.x; c < IN_DIM; c += 256)
        comb[c] = 1.0f / (scales[c] * qs);   // x*comb == (x/scales)/qs (to ~2 ulp)
}

// ---------------- Pass 3: quantize, store (q - zp) as exact bf16 -----------------
// q - zp = clamp(rint(x*comb), -zp, 255-zp)   (zp integral -> clamp shift is exact)
__global__ __launch_bounds__(256) void k_quant(const float* __restrict__ x,
                                               const float* __restrict__ comb,
                                               const float* __restrict__ qp,
                                               unsigned short* __restrict__ xq) {
    const float lo = qp[2], hi = qp[3];
    const int n4 = (M_DIM * IN_DIM) / 4;
    int tid = blockIdx.x * 256 + threadIdx.x;
    const int stride = QBLOCKS * 256;
    for (int i4 = tid; i4 < n4; i4 += stride) {
        int i = i4 * 4;
        float4 xv = *(const float4*)(x + i);
        int c = i % IN_DIM;
        float4 cb = *(const float4*)(comb + c);
        float a[4] = { xv.x * cb.x, xv.y * cb.y, xv.z * cb.z, xv.w * cb.w };
        ushort4 o;
        unsigned short* op = (unsigned short*)&o;
        #pragma unroll
        for (int j = 0; j < 4; j++) {
            float q = rintf(a[j]);
            q = fminf(fmaxf(q, lo), hi);
            op[j] = f2bf(q);                  // integer in [-255,255]: exact in bf16
        }
        *(ushort4*)(xq + i) = o;
    }
}

// ---------------- Pass 4: GEMM  C = qs * (A @ Wc^T) + bias ----------------
// A: [M][K] bf16 (q - zp), Wc: [N][K] bf16, C: [M][N] fp32
#define BM 128
#define BN 128
#define BK 32

__global__ __launch_bounds__(256) void k_gemm(const unsigned short* __restrict__ A,
                                              const unsigned short* __restrict__ Bw,
                                              const float* __restrict__ bias,
                                              const float* __restrict__ qp,
                                              float* __restrict__ C) {
    __shared__ __align__(16) unsigned short As[BM * BK];   // 8 KB
    __shared__ __align__(16) unsigned short Bs[BN * BK];   // 8 KB
    const int tid = threadIdx.x;
    // XCD-aware remap: 2304 blocks, 8 XCDs (round-robin by linear id).
    // Each XCD owns 32 consecutive bm x all 9 bn -> Wc (2.65 MB) L2-resident,
    // each A panel fetched once per XCD-L2 instead of 9x from HBM/L3.
    const int lid = blockIdx.x;
    const int xcd = lid & 7;
    const int kk  = lid >> 3;            // 0..287
    const int bml = kk / 9;              // 0..31
    const int bn  = kk - bml * 9;        // 0..8
    const int bm  = xcd * 32 + bml;      // 0..255
    const int K = IN_DIM, N = OUT_DIM;

    // Staging: 512 segments of 16B per tile; thread t takes segments t and t+256.
    // Segment s -> row s>>2, col8 (s&3)*8. LDS dst = base + lane*16 (wave-uniform base).
    const int r0 = tid >> 2;
    const int c0 = (tid & 3) * 8;
    const unsigned short* ga0 = A  + (size_t)(bm * BM + r0) * K + c0;
    const unsigned short* ga1 = ga0 + (size_t)64 * K;
    const unsigned short* gb0 = Bw + (size_t)(bn * BN + r0) * K + c0;
    const unsigned short* gb1 = gb0 + (size_t)64 * K;
    unsigned short* lA0 = As + tid * 8;
    unsigned short* lA1 = As + tid * 8 + 2048;
    unsigned short* lB0 = Bs + tid * 8;
    unsigned short* lB1 = Bs + tid * 8 + 2048;

    f32x4 acc[4][4];
    #pragma unroll
    for (int mi = 0; mi < 4; mi++)
        #pragma unroll
        for (int ni = 0; ni < 4; ni++)
            acc[mi][ni] = (f32x4)0.0f;

    const int lane = tid & 63, wv = tid >> 6;
    const int wm = (wv & 1) * 64;          // wave m-origin within block tile
    const int wn = (wv >> 1) * 64;         // wave n-origin
    const int l16 = lane & 15, l4 = lane >> 4;
    const bf16x8* Asv = (const bf16x8*)As; // row stride = 4 (in 16B units)
    const bf16x8* Bsv = (const bf16x8*)Bs;
    const int afo = (wm + l16) * 4 + l4;   // A[m=lane&15][k=(lane>>4)*8+j]
    const int bfo = (wn + l16) * 4 + l4;   // B[k][n=lane&15] from Wc[n][k]

    for (int k0 = 0; k0 < K; k0 += BK) {
        __builtin_amdgcn_global_load_lds(
            (const __attribute__((address_space(1))) unsigned int*)(ga0 + k0),
            (__attribute__((address_space(3))) unsigned int*)lA0, 16, 0, 0);
        __builtin_amdgcn_global_load_lds(
            (const __attribute__((address_space(1))) unsigned int*)(ga1 + k0),
            (__attribute__((address_space(3))) unsigned int*)lA1, 16, 0, 0);
        __builtin_amdgcn_global_load_lds(
            (const __attribute__((address_space(1))) unsigned int*)(gb0 + k0),
            (__attribute__((address_space(3))) unsigned int*)lB0, 16, 0, 0);
        __builtin_amdgcn_global_load_lds(
            (const __attribute__((address_space(1))) unsigned int*)(gb1 + k0),
            (__attribute__((address_space(3))) unsigned int*)lB1, 16, 0, 0);
        __syncthreads();                   // drains vmcnt: LDS tiles valid

        bf16x8 af[4], bf[4];
        #pragma unroll
        for (int mi = 0; mi < 4; mi++) af[mi] = Asv[afo + mi * 64];
        #pragma unroll
        for (int ni = 0; ni < 4; ni++) bf[ni] = Bsv[bfo + ni * 64];
        #pragma unroll
        for (int mi = 0; mi < 4; mi++)
            #pragma unroll
            for (int ni = 0; ni < 4; ni++)
                acc[mi][ni] = __builtin_amdgcn_mfma_f32_16x16x32_bf16(
                    af[mi], bf[ni], acc[mi][ni], 0, 0, 0);
        __syncthreads();                   // LDS reads done before next overwrite
    }

    const float qs = qp[0];
    #pragma unroll
    for (int mi = 0; mi < 4; mi++) {
        int row0 = bm * BM + wm + mi * 16 + l4 * 4;
        #pragma unroll
        for (int ni = 0; ni < 4; ni++) {
            int col = bn * BN + wn + ni * 16 + l16;
            float bv = bias[col];
            #pragma unroll
            for (int r = 0; r < 4; r++)
                C[(size_t)(row0 + r) * N + col] = acc[mi][ni][r] * qs + bv;
        }
    }
}

extern "C" void kernel_launch(void* const* d_in, const int* in_sizes, int n_in,
                              void* d_out, int out_size, void* d_ws, size_t ws_size,
                              hipStream_t stream) {
    const float* x      = (const float*)d_in[0];
    const float* qw     = (const float*)d_in[1];
    const float* rw     = (const float*)d_in[2];
    const float* lw     = (const float*)d_in[3];
    const float* bias   = (const float*)d_in[4];
    const float* scales = (const float*)d_in[5];

    char* ws = (char*)d_ws;
    // Workspace layout (all 16B aligned): total ~74.6 MiB
    unsigned short* xq = (unsigned short*)ws;                          // 75,497,472 B
    unsigned short* wc = (unsigned short*)(ws + 75497472);             //  2,654,208 B
    float* partials    = (float*)(ws + 75497472 + 2654208);            //     16,384 B
    float* qp          = (float*)(ws + 75497472 + 2654208 + 16384);    //         64 B
    float* rs          = (float*)(ws + 75497472 + 2654208 + 16384 + 64);        // 4608 B
    float* comb        = (float*)(ws + 75497472 + 2654208 + 16384 + 64 + 4608); // 4608 B

    k_wprep   <<<(OUT_DIM * IN_DIM) / 256, 256, 0, stream>>>(qw, rw, lw, scales, wc, rs);
    k_minmax  <<<RED_BLOCKS, 256, 0, stream>>>(x, rs, partials);
    k_finalize<<<1,          256, 0, stream>>>(partials, scales, qp, comb);
    k_quant   <<<QBLOCKS,    256, 0, stream>>>(x, comb, qp, xq);

    k_gemm<<<2304, 256, 0, stream>>>(xq, wc, bias, qp, (float*)d_out);
}